// Round 12
// baseline (104.521 us; speedup 1.0000x reference)
//
#include <hip/hip_runtime.h>
#include <math.h>

// PCEN v8: single-pass, copy-shaped global traffic, LDS transpose, chained.
//   block = 320 thr; tile = 64 t x 80 f (20 KB); chain = 16 tiles/block.
//   per tile: contiguous stage (dbuf, reg-prefetch 2 ahead, in flight across
//   lgkm-only raw barriers) -> transposed 4-step chunk partials -> one
//   S-Horner per thread (pre = snapshot at k==tc) -> pcen produce in place
//   -> contiguous NT flush. Carry U exact in-chain; chain start = 4-tile
//   (256-step) zero-init halo (truncation a^256 ~ 1.5e-3, validated floor).
//
// M[t] = a*M[t-1] + s*x[t], M[0]=x[0];  u = M/s
// out  = sqrt(x*(M+eps)^-0.98 + 2) - sqrt(2)

#define B_     64
#define T_     8192
#define F4_    20                  // 80 f32 = 20 float4 per timestep
#define TQ_    64                  // timesteps per tile
#define NT_    (T_ / TQ_)          // 128 tiles per seq
#define CH_    4                   // timesteps per chunk (per thread)
#define NC_    (TQ_ / CH_)         // 16 chunks per tile
#define THR_   (F4_ * NC_)         // 320 threads
#define TILE4_ (TQ_ * F4_)         // 1280 float4 per tile (20 KB)
#define LPT_   (TILE4_ / THR_)     // 4 float4 per thread (stage/flush)
#define SPC_   16                  // tiles per chain
#define CHPS_  (NT_ / SPC_)        // 8 chains per seq -> grid 512
#define HALO_  4                   // halo tiles = 256 steps
#define SA_    0.025f
#define AA_    0.975f
#define A4_    0.90368789f         // a^4
#define A4S_   36.147516f          // a^4/s (tile0-chunk0 exact fix, u-space)
#define A64_   0.19783147f         // a^64
#define L2A4_  -0.14610421f        // log2(a^4)

typedef float f4v __attribute__((ext_vector_type(4)));

__device__ __forceinline__ float pcen1(float xv, float m) {
    float l = __builtin_amdgcn_logf(m + 1e-6f);        // v_log_f32 (log2)
    float g = __builtin_amdgcn_exp2f(-0.98f * l);      // (m+eps)^(-alpha)
    return __builtin_amdgcn_sqrtf(fmaf(xv, g, 2.0f)) - 1.4142135623730951f;
}

__device__ __forceinline__ float4 pcen4(float4 xv, float4 m) {
    float4 o;
    o.x = pcen1(xv.x, m.x);
    o.y = pcen1(xv.y, m.y);
    o.z = pcen1(xv.z, m.z);
    o.w = pcen1(xv.w, m.w);
    return o;
}

// d = c*d + v
__device__ __forceinline__ void hstep(float4& d, float c, const float4 v) {
    d.x = fmaf(c, d.x, v.x);
    d.y = fmaf(c, d.y, v.y);
    d.z = fmaf(c, d.z, v.z);
    d.w = fmaf(c, d.w, v.w);
}

// d += c*v
__device__ __forceinline__ void faxpy(float4& d, float c, const float4 v) {
    d.x = fmaf(c, v.x, d.x);
    d.y = fmaf(c, v.y, d.y);
    d.z = fmaf(c, v.z, d.z);
    d.w = fmaf(c, v.w, d.w);
}

// m = a*m + s*x
__device__ __forceinline__ void ema4(float4& m, const float4 xv) {
    m.x = fmaf(AA_, m.x, SA_ * xv.x);
    m.y = fmaf(AA_, m.y, SA_ * xv.y);
    m.z = fmaf(AA_, m.z, SA_ * xv.z);
    m.w = fmaf(AA_, m.w, SA_ * xv.w);
}

// lgkm-only barrier: LDS visibility without draining vmcnt (R9-proven)
__device__ __forceinline__ void lds_barrier() {
    asm volatile("s_waitcnt lgkmcnt(0)" ::: "memory");
    __builtin_amdgcn_s_barrier();
}

__global__ void __launch_bounds__(THR_, 2)
pcen_v8(const float4* __restrict__ x4, float4* __restrict__ o4) {
    __shared__ float4 XT[2][TILE4_];       // double-buffered tile (40 KB)
    __shared__ float4 P[NC_][F4_];         // chunk partials (5 KB)

    const int tid = threadIdx.x;
    const int f4  = tid % F4_;
    const int tc  = tid / F4_;             // chunk 0..15

    const int b     = blockIdx.x / CHPS_;
    const int chain = blockIdx.x % CHPS_;

    const size_t g0 = ((size_t)(b * NT_ + chain * SPC_)) * TILE4_;

    const float powAtc = __builtin_amdgcn_exp2f((float)tc * L2A4_);  // a^(4tc)

    float4 U = make_float4(0.f, 0.f, 0.f, 0.f);
    float4 g[LPT_];

    // ---------- halo: establish U over preceding 256 steps ----------
    if (chain > 0) {                       // block-uniform
        const size_t h0 = g0 - (size_t)HALO_ * TILE4_;
        #pragma unroll
        for (int k = 0; k < LPT_; ++k) g[k] = x4[h0 + tid + k * THR_];

        for (int h = 0; h < HALO_; ++h) {
            lds_barrier();                 // prev P-reads done; XT[h&1] free
            #pragma unroll
            for (int k = 0; k < LPT_; ++k) XT[h & 1][tid + k * THR_] = g[k];
            const size_t nsrc = (h < HALO_ - 1) ? (h0 + (size_t)(h + 1) * TILE4_) : g0;
            #pragma unroll
            for (int k = 0; k < LPT_; ++k) g[k] = x4[nsrc + tid + k * THR_];
            lds_barrier();                 // stage visible

            float4 pu = make_float4(0.f, 0.f, 0.f, 0.f);
            #pragma unroll
            for (int j = 0; j < CH_; ++j)
                hstep(pu, AA_, XT[h & 1][(tc * CH_ + j) * F4_ + f4]);
            P[tc][f4] = pu;
            lds_barrier();                 // P visible

            float4 S = make_float4(0.f, 0.f, 0.f, 0.f);
            #pragma unroll
            for (int k = 0; k < NC_; ++k) hstep(S, A4_, P[k][f4]);
            hstep(U, A64_, S);             // U = a^64*U + S
        }
    } else {
        #pragma unroll
        for (int k = 0; k < LPT_; ++k) g[k] = x4[g0 + tid + k * THR_];
    }

    // ---------- preamble: stage tile 0, prefetch tile 1 ----------
    #pragma unroll
    for (int k = 0; k < LPT_; ++k) XT[0][tid + k * THR_] = g[k];
    #pragma unroll
    for (int k = 0; k < LPT_; ++k) g[k] = x4[g0 + TILE4_ + tid + k * THR_];

    // ---------- main chain loop ----------
    const bool fixchain = (chain == 0);
    int cur = 0;
    #pragma unroll 2
    for (int i = 0; i < SPC_; ++i) {
        lds_barrier();                     // stage(cur) visible; bufs free

        // A: transposed chunk partial
        float4 xv[CH_];
        #pragma unroll
        for (int j = 0; j < CH_; ++j)
            xv[j] = XT[cur][(tc * CH_ + j) * F4_ + f4];
        float4 pu = make_float4(0.f, 0.f, 0.f, 0.f);
        #pragma unroll
        for (int j = 0; j < CH_; ++j) hstep(pu, AA_, xv[j]);
        const bool fix0 = fixchain && (i == 0) && (tc == 0);
        if (fix0) faxpy(pu, A4S_, xv[0]);  // exact M[0]=x[0] (u-space)
        P[tc][f4] = pu;

        // B: stage next tile, issue loads 2 ahead (in flight across barriers)
        if (i < SPC_ - 1) {
            #pragma unroll
            for (int k = 0; k < LPT_; ++k) XT[cur ^ 1][tid + k * THR_] = g[k];
            if (i < SPC_ - 2) {
                const size_t nb = g0 + (size_t)(i + 2) * TILE4_;
                #pragma unroll
                for (int k = 0; k < LPT_; ++k) g[k] = x4[nb + tid + k * THR_];
            }
        }
        lds_barrier();                     // P visible

        // C: one Horner chain; pre(tc) = S-snapshot at k==tc
        float4 S   = make_float4(0.f, 0.f, 0.f, 0.f);
        float4 pre = make_float4(0.f, 0.f, 0.f, 0.f);
        #pragma unroll
        for (int k = 0; k < NC_; ++k) {
            if (k == tc) pre = S;          // cndmask, no divergence
            hstep(S, A4_, P[k][f4]);
        }
        float4 u;
        u.x = fmaf(powAtc, U.x, pre.x);
        u.y = fmaf(powAtc, U.y, pre.y);
        u.z = fmaf(powAtc, U.z, pre.z);
        u.w = fmaf(powAtc, U.w, pre.w);
        hstep(U, A64_, S);                 // U = a^64*U + S (exact in-chain)

        float4 m;                          // m = s*u
        m.x = SA_ * u.x; m.y = SA_ * u.y; m.z = SA_ * u.z; m.w = SA_ * u.w;

        // produce in place (own slots)
        ema4(m, xv[0]);
        if (fix0) faxpy(m, AA_, xv[0]);    // global t=0: m = x[0] exactly
        XT[cur][(tc * CH_) * F4_ + f4] = pcen4(xv[0], m);
        #pragma unroll
        for (int j = 1; j < CH_; ++j) {
            ema4(m, xv[j]);
            XT[cur][(tc * CH_ + j) * F4_ + f4] = pcen4(xv[j], m);
        }
        lds_barrier();                     // produce visible

        // D: contiguous NT flush
        const size_t ob = g0 + (size_t)i * TILE4_;
        #pragma unroll
        for (int k = 0; k < LPT_; ++k) {
            float4 v = XT[cur][tid + k * THR_];
            __builtin_nontemporal_store(*(f4v*)&v, (f4v*)&o4[ob + tid + k * THR_]);
        }
        cur ^= 1;
    }
}

extern "C" void kernel_launch(void* const* d_in, const int* in_sizes, int n_in,
                              void* d_out, int out_size, void* d_ws, size_t ws_size,
                              hipStream_t stream) {
    const float4* x4 = (const float4*)d_in[0];
    float4*       o4 = (float4*)d_out;

    pcen_v8<<<dim3(B_ * CHPS_), dim3(THR_), 0, stream>>>(x4, o4);
}

// Round 13
// 96.632 us; speedup vs baseline: 1.0816x; 1.0816x over previous
//
#include <hip/hip_runtime.h>
#include <math.h>

// PCEN v9 = R9 champion (80.0us) with ONE change: nontemporal stores ->
// plain stores (A/B against R9's recorded counters; NT-write-efficiency
// hypothesis for the 4.2 TB/s effective-BW ceiling).
//   block = 128 thr = 8 seq4 x 16 chunks(16 steps) = 256-step span;
//   each block walks a chain of 4 spans (1024 steps) sequentially.
//   carry = circular 16-chunk (256-step, validated) Horner over 32 LDS rows,
//   weight a^16 -> no serial state. Next-span loads issued BEFORE the
//   barrier; raw s_barrier + lgkmcnt(0) keeps prefetch in flight.
//   halo (256 steps) read once per chain start -> read demand 1.25x.
//
// M[t] = a*M[t-1] + s*x[t], M[0]=x[0]
// out  = sqrt(x*(M+eps)^-0.98 + 2) - sqrt(2)

#define B_      64
#define T_      8192
#define F4_     20                // 80 f32 = 20 float4
#define NSEQ4   (B_ * F4_)        // 1280 float4 lanes
#define SPB_    8                 // seq4 per block
#define CPB_    16                // chunks per span
#define LCH_    16                // steps per chunk
#define SPAN_   (CPB_ * LCH_)     // 256
#define SPC_    4                 // spans per chain
#define CHAIN_  (SPC_ * SPAN_)    // 1024
#define TSPLIT_ (T_ / CHAIN_)     // 8 chains per seq
#define NG_     (NSEQ4 / SPB_)    // 160 seq groups -> grid 1280
#define SA_     0.025f
#define AA_     0.975f
#define A8_     0.81665182f       // 0.975^8
#define A16_    0.66692016f       // 0.975^16
#define A16S_   26.676807f        // A16_/SA_ (chunk-0 exact fix, u-space)

typedef float f4v __attribute__((ext_vector_type(4)));

__device__ __forceinline__ float pcen1(float xv, float m) {
    float l = __builtin_amdgcn_logf(m + 1e-6f);        // v_log_f32 (log2)
    float g = __builtin_amdgcn_exp2f(-0.98f * l);      // (m+eps)^(-alpha)
    return __builtin_amdgcn_sqrtf(fmaf(xv, g, 2.0f)) - 1.4142135623730951f;
}

__device__ __forceinline__ float4 pcen4(float4 xv, float4 m) {
    float4 o;
    o.x = pcen1(xv.x, m.x);
    o.y = pcen1(xv.y, m.y);
    o.z = pcen1(xv.z, m.z);
    o.w = pcen1(xv.w, m.w);
    return o;
}

// d = c*d + v
__device__ __forceinline__ void hstep(float4& d, float c, const float4 v) {
    d.x = fmaf(c, d.x, v.x);
    d.y = fmaf(c, d.y, v.y);
    d.z = fmaf(c, d.z, v.z);
    d.w = fmaf(c, d.w, v.w);
}

// d += c*v
__device__ __forceinline__ void faxpy(float4& d, float c, const float4 v) {
    d.x = fmaf(c, v.x, d.x);
    d.y = fmaf(c, v.y, d.y);
    d.z = fmaf(c, v.z, d.z);
    d.w = fmaf(c, v.w, d.w);
}

// m = a*m + s*x
__device__ __forceinline__ void ema4(float4& m, const float4 xv) {
    m.x = fmaf(AA_, m.x, SA_ * xv.x);
    m.y = fmaf(AA_, m.y, SA_ * xv.y);
    m.z = fmaf(AA_, m.z, SA_ * xv.z);
    m.w = fmaf(AA_, m.w, SA_ * xv.w);
}

// lgkmcnt-only barrier: LDS visibility without draining vmcnt (prefetch
// stays in flight across the barrier).
__device__ __forceinline__ void lds_barrier() {
    asm volatile("s_waitcnt lgkmcnt(0)" ::: "memory");
    __builtin_amdgcn_s_barrier();
}

// One span: partial -> LDS(cur half), prefetch next span, barrier,
// circular Horner carry, barrier, produce + plain stores.
// PB = prev-half base row (16 or 0); cur half = PB^16.
template <int PB, bool PREFETCH>
__device__ __forceinline__ void one_span(
    float4 (&cur)[LCH_], float4 (&nxt)[LCH_],
    const float4* __restrict__ xnext,
    const int s, const int lc,
    const float fixP, const float fixM,
    float4 (*P)[SPB_],
    float4* __restrict__ op)
{
    // ---- u-space partial of cur chunk (two 8-chains) ----
    float4 u0 = make_float4(0.f, 0.f, 0.f, 0.f);
    float4 u1 = make_float4(0.f, 0.f, 0.f, 0.f);
    #pragma unroll
    for (int j = 0; j < 8; ++j) {
        hstep(u0, AA_, cur[j]);
        hstep(u1, AA_, cur[j + 8]);
    }
    float4 pu = u1;
    faxpy(pu, A8_, u0);
    faxpy(pu, fixP, cur[0]);               // chunk-0 exact fix (usually 0)
    P[(PB ^ 16) + lc][s] = pu;

    // ---- prefetch next span (in flight across the barrier) ----
    if (PREFETCH) {
        #pragma unroll
        for (int j = 0; j < LCH_; ++j) nxt[j] = xnext[(size_t)j * F4_];
    }

    lds_barrier();

    // ---- carry: circular 16-term Horner, rows (PB+lc+k)&31, oldest->newest
    float4 u = P[(PB + lc) & 31][s];
    #pragma unroll
    for (int k = 1; k < CPB_; ++k) hstep(u, A16_, P[(PB + lc + k) & 31][s]);

    lds_barrier();                         // reads done before next overwrite

    float4 m;
    m.x = SA_ * u.x; m.y = SA_ * u.y; m.z = SA_ * u.z; m.w = SA_ * u.w;

    // ---- produce: EMA + pcen, PLAIN stores (the single change vs R9) ----
    ema4(m, cur[0]);
    faxpy(m, fixM, cur[0]);                // global t=0: m = x[0] exactly
    op[0] = pcen4(cur[0], m);
    #pragma unroll
    for (int j = 1; j < LCH_; ++j) {
        ema4(m, cur[j]);
        op[(size_t)j * F4_] = pcen4(cur[j], m);
    }
}

__global__ void __launch_bounds__(128, 3)
pcen_chain(const float4* __restrict__ x4, float4* __restrict__ o4) {
    __shared__ float4 P[2 * CPB_][SPB_];   // 32 rows, circular halves

    const int tid = threadIdx.x;
    const int s   = tid & (SPB_ - 1);      // seq4 within block
    const int lc  = tid >> 3;              // chunk 0..15

    const int g     = blockIdx.x % NG_;
    const int chain = blockIdx.x / NG_;

    const int r  = g * SPB_ + s;
    const int b  = r / F4_;
    const int f4 = r - b * F4_;

    const float4* xbase = x4 + (size_t)b * ((size_t)T_ * F4_) + f4;
    float4*       obase = o4 + (size_t)b * ((size_t)T_ * F4_) + f4;

    const int t00 = chain * CHAIN_ + lc * LCH_;   // span-0 chunk start

    float4 xA[LCH_], xB[LCH_];

    // span-0 loads
    const float4* pc = xbase + (size_t)t00 * F4_;
    #pragma unroll
    for (int j = 0; j < LCH_; ++j) xA[j] = pc[(size_t)j * F4_];

    // halo partials -> prev half (rows 16..31); zeros for chain 0
    if (chain > 0) {                       // block-uniform branch
        const float4* ph = pc - (size_t)SPAN_ * F4_;
        #pragma unroll
        for (int j = 0; j < LCH_; ++j) xB[j] = ph[(size_t)j * F4_];
        float4 u0 = make_float4(0.f, 0.f, 0.f, 0.f);
        float4 u1 = make_float4(0.f, 0.f, 0.f, 0.f);
        #pragma unroll
        for (int j = 0; j < 8; ++j) {
            hstep(u0, AA_, xB[j]);
            hstep(u1, AA_, xB[j + 8]);
        }
        float4 hu = u1;
        faxpy(hu, A8_, u0);
        P[CPB_ + lc][s] = hu;
    } else {
        P[CPB_ + lc][s] = make_float4(0.f, 0.f, 0.f, 0.f);
    }

    const bool  c0   = (chain == 0 && lc == 0);
    const float fixP = c0 ? A16S_ : 0.0f;
    const float fixM = c0 ? AA_   : 0.0f;

    float4*       op = obase + (size_t)t00 * F4_;
    const size_t  so = (size_t)SPAN_ * F4_;

    one_span<16, true >(xA, xB, pc + so,     s, lc, fixP, fixM, P, op);
    one_span< 0, true >(xB, xA, pc + 2 * so, s, lc, 0.f,  0.f,  P, op + so);
    one_span<16, true >(xA, xB, pc + 3 * so, s, lc, 0.f,  0.f,  P, op + 2 * so);
    one_span< 0, false>(xB, xA, pc,          s, lc, 0.f,  0.f,  P, op + 3 * so);
}

extern "C" void kernel_launch(void* const* d_in, const int* in_sizes, int n_in,
                              void* d_out, int out_size, void* d_ws, size_t ws_size,
                              hipStream_t stream) {
    const float4* x4 = (const float4*)d_in[0];
    float4*       o4 = (float4*)d_out;

    pcen_chain<<<dim3(NG_ * TSPLIT_), dim3(128), 0, stream>>>(x4, o4);
}

// Round 14
// 62.008 us; speedup vs baseline: 1.6856x; 1.5584x over previous
//
#include <hip/hip_runtime.h>
#include <math.h>

// PCEN v10 = R9 champion (80.0us, NT stores RESTORED — R13 A/B proved NT
// is +17us better than plain) with ONE structural change: SPB_ 8 -> 20.
//   Block = 320 thr = 20 f4 x 16 chunks -> a block owns ALL 20 float4 of
//   one sequence b. Every global load/store instruction covers complete
//   320B feature-rows (line-aligned, no 128B straddle), and per lc-quarter
//   the 16 j-steps tile a contiguous 5KB block -> copy-shaped traffic.
//   Everything else identical to R9: chain of 4 spans (1024 t), circular
//   16-chunk Horner carry (256-step truncation, validated floor 0.0039),
//   prefetch issued before lgkm-only raw barriers (loads stay in flight),
//   raw v_log/v_exp/v_sqrt.
//
// M[t] = a*M[t-1] + s*x[t], M[0]=x[0]
// out  = sqrt(x*(M+eps)^-0.98 + 2) - sqrt(2)

#define B_      64
#define T_      8192
#define F4_     20                // 80 f32 = 20 float4
#define SPB_    20                // f4 per block = ALL of them (full rows)
#define CPB_    16                // chunks per span
#define LCH_    16                // steps per chunk
#define SPAN_   (CPB_ * LCH_)     // 256
#define SPC_    4                 // spans per chain
#define CHAIN_  (SPC_ * SPAN_)    // 1024
#define TSPLIT_ (T_ / CHAIN_)     // 8 chains per seq
#define NG_     B_                // one block per (b, chain) -> grid 512
#define THR_    (SPB_ * CPB_)     // 320 threads = 5 waves
#define SA_     0.025f
#define AA_     0.975f
#define A8_     0.81665182f       // 0.975^8
#define A16_    0.66692016f       // 0.975^16
#define A16S_   26.676807f        // A16_/SA_ (chunk-0 exact fix, u-space)

typedef float f4v __attribute__((ext_vector_type(4)));

__device__ __forceinline__ float pcen1(float xv, float m) {
    float l = __builtin_amdgcn_logf(m + 1e-6f);        // v_log_f32 (log2)
    float g = __builtin_amdgcn_exp2f(-0.98f * l);      // (m+eps)^(-alpha)
    return __builtin_amdgcn_sqrtf(fmaf(xv, g, 2.0f)) - 1.4142135623730951f;
}

__device__ __forceinline__ float4 pcen4(float4 xv, float4 m) {
    float4 o;
    o.x = pcen1(xv.x, m.x);
    o.y = pcen1(xv.y, m.y);
    o.z = pcen1(xv.z, m.z);
    o.w = pcen1(xv.w, m.w);
    return o;
}

// d = c*d + v
__device__ __forceinline__ void hstep(float4& d, float c, const float4 v) {
    d.x = fmaf(c, d.x, v.x);
    d.y = fmaf(c, d.y, v.y);
    d.z = fmaf(c, d.z, v.z);
    d.w = fmaf(c, d.w, v.w);
}

// d += c*v
__device__ __forceinline__ void faxpy(float4& d, float c, const float4 v) {
    d.x = fmaf(c, v.x, d.x);
    d.y = fmaf(c, v.y, d.y);
    d.z = fmaf(c, v.z, d.z);
    d.w = fmaf(c, v.w, d.w);
}

// m = a*m + s*x
__device__ __forceinline__ void ema4(float4& m, const float4 xv) {
    m.x = fmaf(AA_, m.x, SA_ * xv.x);
    m.y = fmaf(AA_, m.y, SA_ * xv.y);
    m.z = fmaf(AA_, m.z, SA_ * xv.z);
    m.w = fmaf(AA_, m.w, SA_ * xv.w);
}

// lgkmcnt-only barrier: LDS visibility without draining vmcnt (prefetch
// stays in flight across the barrier).
__device__ __forceinline__ void lds_barrier() {
    asm volatile("s_waitcnt lgkmcnt(0)" ::: "memory");
    __builtin_amdgcn_s_barrier();
}

// One span: partial -> LDS(cur half), prefetch next span, barrier,
// circular Horner carry, barrier, produce + NT stores.
// PB = prev-half base row (16 or 0); cur half = PB^16.
template <int PB, bool PREFETCH>
__device__ __forceinline__ void one_span(
    float4 (&cur)[LCH_], float4 (&nxt)[LCH_],
    const float4* __restrict__ xnext,
    const int s, const int lc,
    const float fixP, const float fixM,
    float4 (*P)[SPB_],
    float4* __restrict__ op)
{
    // ---- u-space partial of cur chunk (two 8-chains) ----
    float4 u0 = make_float4(0.f, 0.f, 0.f, 0.f);
    float4 u1 = make_float4(0.f, 0.f, 0.f, 0.f);
    #pragma unroll
    for (int j = 0; j < 8; ++j) {
        hstep(u0, AA_, cur[j]);
        hstep(u1, AA_, cur[j + 8]);
    }
    float4 pu = u1;
    faxpy(pu, A8_, u0);
    faxpy(pu, fixP, cur[0]);               // chunk-0 exact fix (usually 0)
    P[(PB ^ 16) + lc][s] = pu;

    // ---- prefetch next span (in flight across the barrier) ----
    if (PREFETCH) {
        #pragma unroll
        for (int j = 0; j < LCH_; ++j) nxt[j] = xnext[(size_t)j * F4_];
    }

    lds_barrier();

    // ---- carry: circular 16-term Horner, rows (PB+lc+k)&31, oldest->newest
    float4 u = P[(PB + lc) & 31][s];
    #pragma unroll
    for (int k = 1; k < CPB_; ++k) hstep(u, A16_, P[(PB + lc + k) & 31][s]);

    lds_barrier();                         // reads done before next overwrite

    float4 m;
    m.x = SA_ * u.x; m.y = SA_ * u.y; m.z = SA_ * u.z; m.w = SA_ * u.w;

    // ---- produce: EMA + pcen, nontemporal stores (R13-validated) ----
    ema4(m, cur[0]);
    faxpy(m, fixM, cur[0]);                // global t=0: m = x[0] exactly
    {
        float4 v = pcen4(cur[0], m);
        __builtin_nontemporal_store(*(f4v*)&v, (f4v*)op);
    }
    #pragma unroll
    for (int j = 1; j < LCH_; ++j) {
        ema4(m, cur[j]);
        float4 v = pcen4(cur[j], m);
        __builtin_nontemporal_store(*(f4v*)&v, (f4v*)(op + (size_t)j * F4_));
    }
}

__global__ void __launch_bounds__(THR_, 2)
pcen_chain(const float4* __restrict__ x4, float4* __restrict__ o4) {
    __shared__ float4 P[2 * CPB_][SPB_];   // 32 rows x 20, circular halves

    const int tid = threadIdx.x;
    const int s   = tid % SPB_;            // f4 index 0..19 (full row)
    const int lc  = tid / SPB_;            // chunk 0..15

    const int b     = blockIdx.x % NG_;    // chain-major: time walks together
    const int chain = blockIdx.x / NG_;

    const float4* xbase = x4 + (size_t)b * ((size_t)T_ * F4_) + s;
    float4*       obase = o4 + (size_t)b * ((size_t)T_ * F4_) + s;

    const int t00 = chain * CHAIN_ + lc * LCH_;   // span-0 chunk start

    float4 xA[LCH_], xB[LCH_];

    // span-0 loads
    const float4* pc = xbase + (size_t)t00 * F4_;
    #pragma unroll
    for (int j = 0; j < LCH_; ++j) xA[j] = pc[(size_t)j * F4_];

    // halo partials -> prev half (rows 16..31); zeros for chain 0
    if (chain > 0) {                       // block-uniform branch
        const float4* ph = pc - (size_t)SPAN_ * F4_;
        #pragma unroll
        for (int j = 0; j < LCH_; ++j) xB[j] = ph[(size_t)j * F4_];
        float4 u0 = make_float4(0.f, 0.f, 0.f, 0.f);
        float4 u1 = make_float4(0.f, 0.f, 0.f, 0.f);
        #pragma unroll
        for (int j = 0; j < 8; ++j) {
            hstep(u0, AA_, xB[j]);
            hstep(u1, AA_, xB[j + 8]);
        }
        float4 hu = u1;
        faxpy(hu, A8_, u0);
        P[CPB_ + lc][s] = hu;
    } else {
        P[CPB_ + lc][s] = make_float4(0.f, 0.f, 0.f, 0.f);
    }

    const bool  c0   = (chain == 0 && lc == 0);
    const float fixP = c0 ? A16S_ : 0.0f;
    const float fixM = c0 ? AA_   : 0.0f;

    float4*       op = obase + (size_t)t00 * F4_;
    const size_t  so = (size_t)SPAN_ * F4_;

    one_span<16, true >(xA, xB, pc + so,     s, lc, fixP, fixM, P, op);
    one_span< 0, true >(xB, xA, pc + 2 * so, s, lc, 0.f,  0.f,  P, op + so);
    one_span<16, true >(xA, xB, pc + 3 * so, s, lc, 0.f,  0.f,  P, op + 2 * so);
    one_span< 0, false>(xB, xA, pc,          s, lc, 0.f,  0.f,  P, op + 3 * so);
}

extern "C" void kernel_launch(void* const* d_in, const int* in_sizes, int n_in,
                              void* d_out, int out_size, void* d_ws, size_t ws_size,
                              hipStream_t stream) {
    const float4* x4 = (const float4*)d_in[0];
    float4*       o4 = (float4*)d_out;

    pcen_chain<<<dim3(NG_ * TSPLIT_), dim3(THR_), 0, stream>>>(x4, o4);
}